// Round 13
// baseline (2769.574 us; speedup 1.0000x reference)
//
#include <hip/hip_runtime.h>

typedef float f32x4 __attribute__((ext_vector_type(4)));
typedef __bf16 bf16x8 __attribute__((ext_vector_type(8)));

#define DI static __device__ __forceinline__

DI unsigned short f2bf(float f) {
  unsigned u = __float_as_uint(f);
  u = (u + 0x7fffu + ((u >> 16) & 1u)) >> 16;
  return (unsigned short)u;
}
DI unsigned pk2(float lo, float hi) {
  return (unsigned)f2bf(lo) | ((unsigned)f2bf(hi) << 16);
}
DI float bflo(unsigned u) { return __uint_as_float(u << 16); }
DI float bfhi(unsigned u) { return __uint_as_float(u & 0xffff0000u); }
DI float sigm(float x) { return 1.0f / (1.0f + expf(-x)); }

DI void gl_lds16(const unsigned short* g, unsigned short* l) {
  __builtin_amdgcn_global_load_lds(
      (const __attribute__((address_space(1))) unsigned int*)g,
      (__attribute__((address_space(3))) unsigned int*)l, 16, 0, 0);
}

DI void st64_sc1(unsigned long long* p, unsigned long long v) {
  __hip_atomic_store(p, v, __ATOMIC_RELAXED, __HIP_MEMORY_SCOPE_AGENT);
}
DI int ldw(const int* p) {
  return __hip_atomic_load(p, __ATOMIC_RELAXED, __HIP_MEMORY_SCOPE_AGENT);
}
DI void stw(int* p, int v) {
  __hip_atomic_store(p, v, __ATOMIC_RELAXED, __HIP_MEMORY_SCOPE_AGENT);
}

DI void burn(int n) {
  float x = (float)(int)threadIdx.x;
#pragma unroll 1
  for (int i = 0; i < n; ++i) x = __builtin_fmaf(x, 1.0000001f, 1e-9f);
  asm volatile("" :: "v"(x));
}

// Dense 4-chain burn for heater blocks (max VALU issue rate).
DI void burn4(int n) {
  float x0 = 1.f + (float)(int)threadIdx.x, x1 = 2.f, x2 = 3.f, x3 = 4.f;
#pragma unroll 1
  for (int i = 0; i < n; ++i) {
    x0 = __builtin_fmaf(x0, 1.0000001f, 1e-9f);
    x1 = __builtin_fmaf(x1, 1.0000001f, 2e-9f);
    x2 = __builtin_fmaf(x2, 1.0000001f, 3e-9f);
    x3 = __builtin_fmaf(x3, 1.0000001f, 4e-9f);
  }
  asm volatile("" :: "v"(x0), "v"(x1), "v"(x2), "v"(x3));
}

// Wait on a replicated release word: ONE load per wave (lane 0), broadcast.
DI void waitrel(const int* relbase, int repl, int target) {
  const int* w = relbase + repl * 32;    // 128B-spaced replicas
  for (;;) {
    int v = 0;
    if ((threadIdx.x & 63) == 0) v = ldw(w);
    v = __shfl(v, 0);
    if (v >= target) break;
    burn(60);
  }
  asm volatile("" ::: "memory");
}
DI void strel(int* relbase, int v) {
  int l = threadIdx.x & 63;
  if (l < 8) stw(relbase + l * 32, v);
}

// Heater: pure-VALU load on idle CUs so the power governor keeps clocks up
// during the latency-critical scans. One uniform poll per ~16k cycles.
DI void heater(const int* relbase, int repl, int exitval) {
  const int* w = relbase + repl * 32;
  for (;;) {
    burn4(4000);
    if (ldw(w) >= exitval) break;
  }
}

// ---------------------------------------------------------------------------
__global__ void k_fold(const float* __restrict__ tW, const float* __restrict__ tb,
                       const float* __restrict__ hW, const float* __restrict__ hb,
                       const float* __restrict__ cW, const float* __restrict__ cb,
                       const float* __restrict__ tiW, const float* __restrict__ tib,
                       const float* __restrict__ oW, const float* __restrict__ ob,
                       const float* __restrict__ fiW, const float* __restrict__ fib,
                       float* __restrict__ M, float* __restrict__ b0v)
{
  int g = blockIdx.x * 256 + threadIdx.x;
  if (g >= 1024 * 17) return;
  int h = g / 17, f = g - h * 17;
  const float* fw = fiW + (size_t)h * 2048;
  float s = 0.f;
  if (f == 16) {
    for (int k = 0; k < 256; ++k) s += fw[k] * tb[k];
    for (int k = 0; k < 256; ++k) s += fw[256 + k] * hb[k];
    for (int k = 0; k < 256; ++k) s += fw[512 + k] * cb[k];
    for (int k = 0; k < 256; ++k) s += fw[768 + k] * tib[k];
    for (int r = 0; r < 1024; ++r) s += fw[1024 + r] * ob[r];
    b0v[h] = s + fib[h];
  } else if (f == 0) {
    for (int k = 0; k < 256; ++k) s += fw[k] * tW[k];
    M[h * 16 + 0] = s;
  } else if (f == 1) {
    for (int k = 0; k < 256; ++k) s += fw[256 + k] * hW[k];
    M[h * 16 + 1] = s;
  } else if (f == 2) {
    for (int k = 0; k < 256; ++k) s += fw[512 + k] * cW[k];
    M[h * 16 + 2] = s;
  } else if (f == 11) {
    for (int k = 0; k < 256; ++k) s += fw[768 + k] * tiW[2 * k];
    M[h * 16 + 11] = s;
  } else if (f == 12) {
    for (int k = 0; k < 256; ++k) s += fw[768 + k] * tiW[2 * k + 1];
    M[h * 16 + 12] = s;
  } else {
    int col = (f <= 10) ? (f - 3) : (f - 5);
    for (int r = 0; r < 1024; ++r) s += fw[1024 + r] * oW[r * 11 + col];
    M[h * 16 + f] = s;
  }
}

__global__ __launch_bounds__(256)
void k_proj(const float* __restrict__ feat, const float* __restrict__ M,
            const float* __restrict__ b0v, unsigned short* __restrict__ proj)
{
  __shared__ float ft[16];
  int bs = blockIdx.x;
  int h = blockIdx.y * 256 + threadIdx.x;
  if (threadIdx.x < 16) ft[threadIdx.x] = feat[bs * 16 + threadIdx.x];
  __syncthreads();
  float sum = b0v[h];
  const float* mr = M + h * 16;
#pragma unroll
  for (int f = 0; f < 16; ++f) sum += mr[f] * ft[f];
  proj[(size_t)bs * 1024 + h] = f2bf(tanhf(sum));
}

__global__ void k_conv(const float* __restrict__ s, unsigned short* __restrict__ d, int n8)
{
  for (long i = (long)blockIdx.x * 256 + threadIdx.x; i < n8; i += (long)gridDim.x * 256) {
    const float* p = s + i * 8;
    f32x4 a = *(const f32x4*)p, b = *(const f32x4*)(p + 4);
    uint4 o;
    o.x = pk2(a[0], a[1]); o.y = pk2(a[2], a[3]);
    o.z = pk2(b[0], b[1]); o.w = pk2(b[2], b[3]);
    *(uint4*)(d + i * 8) = o;
  }
}

__global__ void k_conv_str(const float* __restrict__ s, unsigned short* __restrict__ d, int coff)
{
  int r = blockIdx.x;
  int c = threadIdx.x * 4;
  f32x4 a = *(const f32x4*)(s + (size_t)r * 2048 + coff + c);
  uint2 o; o.x = pk2(a[0], a[1]); o.y = pk2(a[2], a[3]);
  *(uint2*)(d + (size_t)r * 1024 + c) = o;
}

__global__ void k_gather_e(const int* __restrict__ toks, const float* __restrict__ emb,
                           unsigned short* __restrict__ e_bf)
{
  int row = blockIdx.x;               // 2048
  int t = row >> 5, b = row & 31;
  unsigned short* dst = e_bf + (size_t)row * 1024 + threadIdx.x * 4;
  if (t < 63) {
    int tok = toks[b * 64 + t];
    f32x4 a = *(const f32x4*)(emb + (size_t)tok * 1024 + threadIdx.x * 4);
    uint2 o; o.x = pk2(a[0], a[1]); o.y = pk2(a[2], a[3]);
    *(uint2*)dst = o;
  } else {
    uint2 o; o.x = 0u; o.y = 0u;
    *(uint2*)dst = o;
  }
}

__global__ void k_onehot(const int* __restrict__ toks, float* __restrict__ out)
{
  int i = blockIdx.x * 256 + threadIdx.x;
  if (i >= 32 * 32000) return;
  int b = i / 32000, v = i - b * 32000;
  out[(size_t)b * 64 * 32000 + v] = (v == toks[0]) ? 1.0f : 0.0f;
}

// ---------------------------------------------------------------------------
// bf16 MFMA GEMM: C[M,N] = A[M,K]*B[N,K]^T + bias[N]
// MODE 0: f32 C; MODE 1: bf16 C; MODE 2: decoder-output remap; MODE 3: bf16 C^T
// ---------------------------------------------------------------------------
template<int MODE>
__global__ __launch_bounds__(256)
void gemm_bf(const unsigned short* __restrict__ A, const unsigned short* __restrict__ B,
             const float* __restrict__ bias, float* __restrict__ Cf,
             unsigned short* __restrict__ Cb,
             int tiles_m, int K, int lda, int ldb, int ldc, int coloff)
{
  __shared__ unsigned short As[4096];
  __shared__ unsigned short Bs[4096];
  const int nblk = gridDim.x;
  const int cpx = nblk >> 3;
  const int bid = blockIdx.x;
  const int id = (bid & 7) * cpx + (bid >> 3);
  const int tm = id % tiles_m, tn = id / tiles_m;
  const int tid = threadIdx.x;
  const int lane = tid & 63, wave = tid >> 6;
  const int wm = (wave & 1) << 6, wn = (wave >> 1) << 6;
  const int r0 = tid >> 2, kc0 = (tid & 3) << 3;
  const unsigned short* ga0 = A + (size_t)(tm * 128 + r0) * lda + kc0;
  const unsigned short* ga1 = A + (size_t)(tm * 128 + 64 + r0) * lda + kc0;
  const unsigned short* gb0 = B + (size_t)(tn * 128 + r0) * ldb + kc0;
  const unsigned short* gb1 = B + (size_t)(tn * 128 + 64 + r0) * ldb + kc0;
  const int lr = lane & 15, lkb = (lane >> 4) << 3;

  f32x4 acc[4][4];
#pragma unroll
  for (int m = 0; m < 4; ++m)
#pragma unroll
    for (int n = 0; n < 4; ++n) { acc[m][n][0]=0.f; acc[m][n][1]=0.f; acc[m][n][2]=0.f; acc[m][n][3]=0.f; }

  for (int kt = 0; kt < K; kt += 32) {
    __syncthreads();
    gl_lds16(ga0 + kt, &As[tid * 8]);
    gl_lds16(ga1 + kt, &As[(tid + 256) * 8]);
    gl_lds16(gb0 + kt, &Bs[tid * 8]);
    gl_lds16(gb1 + kt, &Bs[(tid + 256) * 8]);
    __syncthreads();
    bf16x8 af[4], bfv[4];
#pragma unroll
    for (int m = 0; m < 4; ++m) af[m] = *(const bf16x8*)&As[(wm + m * 16 + lr) * 32 + lkb];
#pragma unroll
    for (int n = 0; n < 4; ++n) bfv[n] = *(const bf16x8*)&Bs[(wn + n * 16 + lr) * 32 + lkb];
#pragma unroll
    for (int m = 0; m < 4; ++m)
#pragma unroll
      for (int n = 0; n < 4; ++n)
        acc[m][n] = __builtin_amdgcn_mfma_f32_16x16x32_bf16(af[m], bfv[n], acc[m][n], 0, 0, 0);
  }

#pragma unroll
  for (int m = 0; m < 4; ++m) {
    int rb = tm * 128 + wm + m * 16 + ((lane >> 4) << 2);
#pragma unroll
    for (int n = 0; n < 4; ++n) {
      int c = tn * 128 + wn + n * 16 + lr;
      float bb = bias[c];
#pragma unroll
      for (int i = 0; i < 4; ++i) {
        float v = acc[m][n][i] + bb;
        int r = rb + i;
        if (MODE == 0) {
          Cf[(size_t)r * ldc + c] = v;
        } else if (MODE == 1) {
          Cb[(size_t)r * ldc + c] = f2bf(v);
        } else if (MODE == 3) {
          Cb[(size_t)c * 4096 + r] = f2bf(v);
        } else {
          if (r < 2016) {
            int t = r >> 5, b2 = r & 31;
            Cf[((size_t)b2 * 64 + t + 1) * 32000 + coloff + c] = v;
          }
        }
      }
    }
  }
}

// ---------------------------------------------------------------------------
// Persistent encoder scan. 64 worker blocks + 1 master + 191 heaters (256).
// ---------------------------------------------------------------------------
__global__ __launch_bounds__(256, 1)
void k_enc_scan(const float* __restrict__ gi_all, const float* __restrict__ whh,
                const float* __restrict__ bhh, float* __restrict__ hfp,
                unsigned short* __restrict__ enc_bf,
                int* __restrict__ arrE, int* __restrict__ relE)
{
  const int tid = threadIdx.x;
  const int blk = blockIdx.x;
  if (blk > 64) {                          // heater blocks
    heater(relE, blk & 7, 127);
    return;
  }
  if (blk == 64) {
    if (tid < 64) {
      for (int g = 1; g <= 127; ++g) {
        for (;;) {
          int v = ldw(&arrE[tid << 3]);
          if (__all(v >= g)) break;
          burn(60);
        }
        asm volatile("" ::: "memory");
        strel(relE, g);
      }
    }
    return;
  }

  __shared__ unsigned short W[48 * 1024];
  __shared__ float Cred[4 * 2 * 3 * 64 * 4];
  const int lane = tid & 63, wave = tid >> 6;
  const int j0 = blk * 16;
  const int repl = blk & 7;

  for (int i = tid; i < 48 * 128; i += 256) {
    int r = i >> 7, c = i & 127;
    int gr = ((r >> 4) << 10) + j0 + (r & 15);
    const float* src = whh + ((size_t)gr << 10) + (c << 3);
    f32x4 a = *(const f32x4*)src, b = *(const f32x4*)(src + 4);
    uint4 o;
    o.x = pk2(a[0], a[1]); o.y = pk2(a[2], a[3]);
    o.z = pk2(b[0], b[1]); o.w = pk2(b[2], b[3]);
    *(uint4*)&W[(r << 10) + ((c ^ (r & 7)) << 3)] = o;
  }
  __syncthreads();

  int cb[2], cj[2], clb[2], creg[2], cm[2];
  float bh0[2], bh1[2], bh2[2];
  float hp[2] = {0.f, 0.f};
#pragma unroll
  for (int cc = 0; cc < 2; ++cc) {
    int cell = tid + (cc << 8);
    cb[cc] = cell >> 4; cj[cc] = cell & 15;
    clb[cc] = ((cb[cc] & 15) >> 2) * 16;
    creg[cc] = cb[cc] & 3; cm[cc] = cb[cc] >> 4;
    bh0[cc] = bhh[j0 + cj[cc]];
    bh1[cc] = bhh[1024 + j0 + cj[cc]];
    bh2[cc] = bhh[2048 + j0 + cj[cc]];
  }

#pragma unroll 1
  for (int s = 0; s < 128; ++s) {
    float gp[2][3];
#pragma unroll
    for (int cc = 0; cc < 2; ++cc) {
      const float* gi = gi_all + ((size_t)cb[cc] * 128 + s) * 3072 + j0 + cj[cc];
      gp[cc][0] = gi[0]; gp[cc][1] = gi[1024]; gp[cc][2] = gi[2048];
    }

    f32x4 acc[2][3];
#pragma unroll
    for (int m = 0; m < 2; ++m)
#pragma unroll
      for (int n = 0; n < 3; ++n) { acc[m][n][0]=0.f; acc[m][n][1]=0.f; acc[m][n][2]=0.f; acc[m][n][3]=0.f; }

    if (s > 0) {
      waitrel(relE, repl, s);
      const unsigned short* hr = enc_bf + (size_t)(s - 1) * 1024;
      const int k0 = wave << 8;
      bf16x8 af[2][8];
#pragma unroll
      for (int kk = 0; kk < 8; ++kk) {
        int k = k0 + kk * 32 + ((lane >> 4) << 3);
        af[0][kk] = *(const bf16x8*)(hr + (size_t)(lane & 15) * 131072 + k);
        af[1][kk] = *(const bf16x8*)(hr + (size_t)(16 + (lane & 15)) * 131072 + k);
      }
#pragma unroll
      for (int kk = 0; kk < 8; ++kk) {
        int c = ((k0 + kk * 32) >> 3) + (lane >> 4);
#pragma unroll
        for (int n = 0; n < 3; ++n) {
          int wr = n * 16 + (lane & 15);
          bf16x8 bfr = *(const bf16x8*)&W[(wr << 10) + ((c ^ (wr & 7)) << 3)];
          acc[0][n] = __builtin_amdgcn_mfma_f32_16x16x32_bf16(af[0][kk], bfr, acc[0][n], 0, 0, 0);
          acc[1][n] = __builtin_amdgcn_mfma_f32_16x16x32_bf16(af[1][kk], bfr, acc[1][n], 0, 0, 0);
        }
      }
    }
#pragma unroll
    for (int m = 0; m < 2; ++m)
#pragma unroll
      for (int n = 0; n < 3; ++n)
        *(f32x4*)&Cred[((((wave * 2 + m) * 3 + n) * 64) + lane) << 2] = acc[m][n];
    __syncthreads();

    float h2v[2];
#pragma unroll
    for (int cc = 0; cc < 2; ++cc) {
      int lj = clb[cc] + cj[cc], reg = creg[cc], m = cm[cc];
      float Cr = 0.f, Cz = 0.f, Cn = 0.f;
#pragma unroll
      for (int w = 0; w < 4; ++w) {
        Cr += Cred[((((w * 2 + m) * 3 + 0) * 64 + lj) << 2) + reg];
        Cz += Cred[((((w * 2 + m) * 3 + 1) * 64 + lj) << 2) + reg];
        Cn += Cred[((((w * 2 + m) * 3 + 2) * 64 + lj) << 2) + reg];
      }
      float r = sigm(gp[cc][0] + Cr + bh0[cc]);
      float z = sigm(gp[cc][1] + Cz + bh1[cc]);
      float n = tanhf(gp[cc][2] + r * (Cn + bh2[cc]));
      float h2 = (1.f - z) * n + z * hp[cc];
      h2v[cc] = h2; hp[cc] = h2;
    }
    if (s == 127) {
      hfp[cb[0] * 1024 + j0 + cj[0]] = h2v[0];
      hfp[cb[1] * 1024 + j0 + cj[1]] = h2v[1];
    }
#pragma unroll
    for (int cc = 0; cc < 2; ++cc) {
      unsigned short sv = f2bf(h2v[cc]);
      unsigned p = (unsigned)sv | (((unsigned)__shfl_xor((int)(unsigned)sv, 1)) << 16);
      unsigned q = (unsigned)__shfl_xor((int)p, 2);
      if ((tid & 3) == 0) {
        unsigned long long dv = (unsigned long long)p | ((unsigned long long)q << 32);
        st64_sc1((unsigned long long*)&enc_bf[((size_t)cb[cc] * 128 + s) * 1024 + j0 + cj[cc]], dv);
      }
    }
    __syncthreads();
    if (tid == 0) stw(&arrE[blk << 3], s + 1);
  }
}

// ---------------------------------------------------------------------------
// Persistent decoder scan. 64 attn + 128 GRU + 1 master + 63 heaters (256).
// relD monotonic: 2t+1 = e(t) ready, 2t+2 = h(t) ready.
// ---------------------------------------------------------------------------
__global__ __launch_bounds__(256, 1)
void k_dec_scan(const float* __restrict__ gi_e, const float* __restrict__ whh,
                const float* __restrict__ bhh,
                const unsigned short* __restrict__ keys,
                const unsigned short* __restrict__ enc_bf,
                unsigned short* __restrict__ hcat, const float* __restrict__ hfp0,
                const unsigned short* __restrict__ xeT, float* __restrict__ w_all,
                int* __restrict__ arrW, int* __restrict__ arrH,
                int* __restrict__ relD)
{
  static __shared__ __attribute__((aligned(16))) char smem[135168];
  const int tid = threadIdx.x;
  const int blk = blockIdx.x;
  const int repl = blk & 7;

  if (blk > 192) {                         // heater blocks
    heater(relD, blk & 7, 126);
    return;
  }
  if (blk == 192) {                        // master
    if (tid < 64) {
      for (int t = 0; t < 63; ++t) {
        for (;;) {                         // all 64 attn halves published e(t)
          int v = ldw(&arrW[tid << 3]);
          if (__all(v >= t + 1)) break;
          burn(60);
        }
        asm volatile("" ::: "memory");
        strel(relD, 2 * t + 1);
        for (;;) {                         // all 128 GRU blocks published h(t)
          int v0 = ldw(&arrH[(tid * 2) << 4]);
          int v1 = ldw(&arrH[(tid * 2 + 1) << 4]);
          if (__all(v0 >= t + 1 && v1 >= t + 1)) break;
          burn(60);
        }
        asm volatile("" ::: "memory");
        strel(relD, 2 * t + 2);
      }
    }
    return;
  }

  if (blk < 64) {
    // ------------------------- attention half-blocks ----------------------
    unsigned short* Ks = (unsigned short*)smem;            // 64 x 1024 bf16 (128KB)
    unsigned short* hsh = (unsigned short*)(smem + 131072); // 1024 bf16
    float* parr = (float*)(smem + 133120);                  // 4 x 64 f32
    const int b = blk >> 1, half = blk & 1;
    const int lane = tid & 63, wave = tid >> 6;

    // stage this half's 64 key rows into LDS, XOR-swizzled 16B chunks
    for (int i = tid; i < 64 * 128; i += 256) {
      int s = i >> 7, c = i & 127;
      uint4 kv = *(const uint4*)(keys + ((size_t)(b * 128 + half * 64 + s) << 10) + (c << 3));
      *(uint4*)&Ks[(s << 10) + ((c ^ (s & 7)) << 3)] = kv;
    }
    __syncthreads();

#pragma unroll 1
    for (int t = 0; t < 63; ++t) {
      if (t) waitrel(relD, repl, 2 * t);   // h(t-1) published
      const unsigned short* hsrc = (t == 0)
          ? (enc_bf + (size_t)b * 131072 + (size_t)127 * 1024)
          : (hcat + ((size_t)(t - 1) * 32 + b) * 2048);
      *(uint2*)&hsh[tid * 4] = *(const uint2*)(hsrc + tid * 4);
      __syncthreads();
      // wave handles k quarter; lane = s row
      float a0 = 0.f, a1 = 0.f;
#pragma unroll 8
      for (int i = 0; i < 32; i += 2) {
        int c0 = wave * 32 + i, c1 = c0 + 1;
        uint4 kv0 = *(const uint4*)&Ks[(lane << 10) + ((c0 ^ (lane & 7)) << 3)];
        uint4 kv1 = *(const uint4*)&Ks[(lane << 10) + ((c1 ^ (lane & 7)) << 3)];
        uint4 hv0 = *(const uint4*)&hsh[c0 << 3];
        uint4 hv1 = *(const uint4*)&hsh[c1 << 3];
        a0 += bflo(kv0.x) * bflo(hv0.x) + bfhi(kv0.x) * bfhi(hv0.x)
            + bflo(kv0.y) * bflo(hv0.y) + bfhi(kv0.y) * bfhi(hv0.y)
            + bflo(kv0.z) * bflo(hv0.z) + bfhi(kv0.z) * bfhi(hv0.z)
            + bflo(kv0.w) * bflo(hv0.w) + bfhi(kv0.w) * bfhi(hv0.w);
        a1 += bflo(kv1.x) * bflo(hv1.x) + bfhi(kv1.x) * bfhi(hv1.x)
            + bflo(kv1.y) * bflo(hv1.y) + bfhi(kv1.y) * bfhi(hv1.y)
            + bflo(kv1.z) * bflo(hv1.z) + bfhi(kv1.z) * bfhi(hv1.z)
            + bflo(kv1.w) * bflo(hv1.w) + bfhi(kv1.w) * bfhi(hv1.w);
      }
      parr[wave * 64 + lane] = a0 + a1;
      __syncthreads();
      if (tid < 64) {
        float sc = (parr[tid] + parr[64 + tid] + parr[128 + tid] + parr[192 + tid]) * 0.03125f;
        float e = expf(sc);                // raw-e softmax: consumers normalize
        float eo = __shfl_xor(e, 1);
        if ((tid & 1) == 0) {
          unsigned long long dv = (unsigned long long)__float_as_uint(e)
                                | ((unsigned long long)__float_as_uint(eo) << 32);
          st64_sc1((unsigned long long*)(w_all + ((size_t)t * 32 + b) * 128 + half * 64 + tid), dv);
        }
      }
      __syncthreads();                     // drain e stores
      if (tid == 0) stw(&arrW[blk << 3], t + 1);
    }
    return;
  }

  // --------------------------- GRU blocks ---------------------------------
  unsigned short* Wh = (unsigned short*)smem;              // 32 x 1024 bf16 (64KB)
  float* Cred = (float*)(smem + 65536);                    // 16KB
  const int lane = tid & 63, wave = tid >> 6;
  const int gblk = blk - 64;               // 0..127
  const int j0 = gblk * 8;

  for (int i = tid; i < 32 * 128; i += 256) {
    int r = i >> 7, c = i & 127;
    int off = (r << 10) + ((c ^ (r & 7)) << 3);
    uint4 oh;
    oh.x = oh.y = oh.z = oh.w = 0u;
    if (r < 24) {
      int gr = ((r >> 3) << 10) + j0 + (r & 7);
      const float* sh = whh + ((size_t)gr << 10) + (c << 3);
      f32x4 a = *(const f32x4*)sh, b = *(const f32x4*)(sh + 4);
      oh.x = pk2(a[0], a[1]); oh.y = pk2(a[2], a[3]);
      oh.z = pk2(b[0], b[1]); oh.w = pk2(b[2], b[3]);
    }
    *(uint4*)&Wh[off] = oh;
  }
  __syncthreads();

  const int gb = tid >> 3, gj = tid & 7;
  const int glb = ((gb & 15) >> 2) * 16;
  const int greg = gb & 3, gm = gb >> 4;
  const float bh0 = bhh[j0 + gj];
  const float bh1 = bhh[1024 + j0 + gj];
  const float bh2 = bhh[2048 + j0 + gj];
  float hpv = hfp0[gb * 1024 + j0 + gj];

  // t-invariant xeT slice -> registers (48 uint4 = 768B/thread)
  uint4 x0v[16], x1v[16], x2v[16];
  {
    const unsigned short* x0 = xeT + ((size_t)(j0 + gj) << 12) + gb * 128;
    const unsigned short* x1 = xeT + ((size_t)(1024 + j0 + gj) << 12) + gb * 128;
    const unsigned short* x2 = xeT + ((size_t)(2048 + j0 + gj) << 12) + gb * 128;
#pragma unroll
    for (int i = 0; i < 16; ++i) {
      x0v[i] = *(const uint4*)(x0 + i * 8);
      x1v[i] = *(const uint4*)(x1 + i * 8);
      x2v[i] = *(const uint4*)(x2 + i * 8);
    }
  }

#pragma unroll 1
  for (int t = 0; t < 63; ++t) {
    const float* gie = gi_e + ((size_t)t * 32 + gb) * 3072 + j0 + gj;
    float g0 = gie[0], g1 = gie[1024], g2 = gie[2048];

    if (t) waitrel(relD, repl, 2 * t);     // h(t-1) published
    const unsigned short* abase;
    size_t astr;
    if (t == 0) { abase = enc_bf + (size_t)127 * 1024; astr = 131072; }
    else { abase = hcat + (size_t)(t - 1) * 32 * 2048; astr = 2048; }
    const int k0 = wave << 8;
    f32x4 acc[2][2];
#pragma unroll
    for (int m = 0; m < 2; ++m)
#pragma unroll
      for (int n = 0; n < 2; ++n) { acc[m][n][0]=0.f; acc[m][n][1]=0.f; acc[m][n][2]=0.f; acc[m][n][3]=0.f; }
    {
      bf16x8 af[2][8];
#pragma unroll
      for (int kk = 0; kk < 8; ++kk) {
        int k = k0 + kk * 32 + ((lane >> 4) << 3);
        af[0][kk] = *(const bf16x8*)(abase + (size_t)(lane & 15) * astr + k);
        af[1][kk] = *(const bf16x8*)(abase + (size_t)(16 + (lane & 15)) * astr + k);
      }
#pragma unroll
      for (int kk = 0; kk < 8; ++kk) {
        int c = ((k0 + kk * 32) >> 3) + (lane >> 4);
#pragma unroll
        for (int n = 0; n < 2; ++n) {
          int wr = n * 16 + (lane & 15);
          bf16x8 bfr = *(const bf16x8*)&Wh[(wr << 10) + ((c ^ (wr & 7)) << 3)];
          acc[0][n] = __builtin_amdgcn_mfma_f32_16x16x32_bf16(af[0][kk], bfr, acc[0][n], 0, 0, 0);
          acc[1][n] = __builtin_amdgcn_mfma_f32_16x16x32_bf16(af[1][kk], bfr, acc[1][n], 0, 0, 0);
        }
      }
    }
#pragma unroll
    for (int m = 0; m < 2; ++m)
#pragma unroll
      for (int n = 0; n < 2; ++n)
        *(f32x4*)&Cred[((((wave * 2 + m) * 2 + n) * 64) + lane) << 2] = acc[m][n];
    __syncthreads();

    // wait for raw e's, then ctx-path = (sum_s e_s * xe) / sum_s e_s
    waitrel(relD, repl, 2 * t + 1);
    const float* wrow = w_all + ((size_t)t * 32 + gb) * 128;
    float se = 0.f, cx0 = 0.f, cx1 = 0.f, cx2 = 0.f;
#pragma unroll
    for (int i = 0; i < 16; ++i) {
      f32x4 wa = *(const f32x4*)(wrow + i * 8);
      f32x4 wb2 = *(const f32x4*)(wrow + i * 8 + 4);
      se += (wa[0] + wa[1]) + (wa[2] + wa[3]) + (wb2[0] + wb2[1]) + (wb2[2] + wb2[3]);
      uint4 a0 = x0v[i], a1 = x1v[i], a2 = x2v[i];
      cx0 += wa[0]*bflo(a0.x) + wa[1]*bfhi(a0.x) + wa[2]*bflo(a0.y) + wa[3]*bfhi(a0.y)
           + wb2[0]*bflo(a0.z) + wb2[1]*bfhi(a0.z) + wb2[2]*bflo(a0.w) + wb2[3]*bfhi(a0.w);
      cx1 += wa[0]*bflo(a1.x) + wa[1]*bfhi(a1.x) + wa[2]*bflo(a1.y) + wa[3]*bfhi(a1.y)
           + wb2[0]*bflo(a1.z) + wb2[1]*bfhi(a1.z) + wb2[2]*bflo(a1.w) + wb2[3]*bfhi(a1.w);
      cx2 += wa[0]*bflo(a2.x) + wa[1]*bfhi(a2.x) + wa[2]*bflo(a2.y) + wa[3]*bfhi(a2.y)
           + wb2[0]*bflo(a2.z) + wb2[1]*bfhi(a2.z) + wb2[2]*bflo(a2.w) + wb2[3]*bfhi(a2.w);
    }
    float inv = 1.f / se;
    cx0 *= inv; cx1 *= inv; cx2 *= inv;

    {
      float Chr = 0.f, Chz = 0.f, Chn = 0.f;
#pragma unroll
      for (int w = 0; w < 4; ++w) {
        Chr += Cred[((((w * 2 + gm) * 2 + 0) * 64 + glb + gj) << 2) + greg];
        Chz += Cred[((((w * 2 + gm) * 2 + 0) * 64 + glb + gj + 8) << 2) + greg];
        Chn += Cred[((((w * 2 + gm) * 2 + 1) * 64 + glb + gj) << 2) + greg];
      }
      float r = sigm(g0 + cx0 + Chr + bh0);
      float z = sigm(g1 + cx1 + Chz + bh1);
      float n2 = tanhf(g2 + cx2 + r * (Chn + bh2));
      float h2 = (1.f - z) * n2 + z * hpv;
      hpv = h2;
      unsigned short sv = f2bf(h2);
      unsigned p = (unsigned)sv | (((unsigned)__shfl_xor((int)(unsigned)sv, 1)) << 16);
      unsigned q = (unsigned)__shfl_xor((int)p, 2);
      if ((tid & 3) == 0) {
        unsigned long long dv = (unsigned long long)p | ((unsigned long long)q << 32);
        st64_sc1((unsigned long long*)&hcat[((size_t)t * 32 + gb) * 2048 + j0 + gj], dv);
      }
    }
    __syncthreads();
    if (tid == 0) stw(&arrH[gblk << 4], t + 1);
  }
}

// ---------------------------------------------------------------------------
// Post-scan ctx assembly: hcat[t*32+b][1024+j] = sum_s w*enc / sum_s w
// ---------------------------------------------------------------------------
__global__ __launch_bounds__(256)
void k_ctx(const float* __restrict__ w_all, const unsigned short* __restrict__ enc_bf,
           unsigned short* __restrict__ hcat)
{
  __shared__ float wsh[8][128];
  __shared__ float inv[8];
  const int b = blockIdx.x, tg = blockIdx.y;
  const int t0 = tg * 8;
  const int nt = (t0 + 8 <= 63) ? 8 : (63 - t0);
  const int tid = threadIdx.x;
  for (int idx = tid; idx < 8 * 128; idx += 256) {
    int tt = idx >> 7, s = idx & 127;
    wsh[tt][s] = (tt < nt) ? w_all[((size_t)(t0 + tt) * 32 + b) * 128 + s] : 0.f;
  }
  __syncthreads();
  if (tid < 8) {
    float s = 0.f;
    for (int i = 0; i < 128; ++i) s += wsh[tid][i];
    inv[tid] = (tid < nt) ? 1.f / s : 0.f;
  }
  __syncthreads();
  const int j0 = tid * 4;
  f32x4 cacc[8];
#pragma unroll
  for (int tt = 0; tt < 8; ++tt) { cacc[tt][0]=0.f; cacc[tt][1]=0.f; cacc[tt][2]=0.f; cacc[tt][3]=0.f; }
  const unsigned short* eb = enc_bf + ((size_t)b << 17) + j0;
  for (int s = 0; s < 128; ++s) {
    uint2 ev = *(const uint2*)(eb + ((size_t)s << 10));
    float v0 = bflo(ev.x), v1 = bfhi(ev.x), v2 = bflo(ev.y), v3 = bfhi(ev.y);
#pragma unroll
    for (int tt = 0; tt < 8; ++tt) {
      float w = wsh[tt][s];
      cacc[tt][0] += w * v0; cacc[tt][1] += w * v1;
      cacc[tt][2] += w * v2; cacc[tt][3] += w * v3;
    }
  }
#pragma unroll
  for (int tt = 0; tt < 8; ++tt) {
    if (tt < nt) {
      float iv = inv[tt];
      uint2 co;
      co.x = pk2(cacc[tt][0] * iv, cacc[tt][1] * iv);
      co.y = pk2(cacc[tt][2] * iv, cacc[tt][3] * iv);
      *(uint2*)(hcat + ((size_t)(t0 + tt) * 32 + b) * 2048 + 1024 + j0) = co;
    }
  }
}

// ---------------------------------------------------------------------------
extern "C" void kernel_launch(void* const* d_in, const int* in_sizes, int n_in,
                              void* d_out, int out_size, void* d_ws, size_t ws_size,
                              hipStream_t stream)
{
  const float* features = (const float*)d_in[0];
  const int*   toks     = (const int*)d_in[1];
  const float* temp_W = (const float*)d_in[2];  const float* temp_b = (const float*)d_in[3];
  const float* hum_W  = (const float*)d_in[4];  const float* hum_b  = (const float*)d_in[5];
  const float* cloud_W= (const float*)d_in[6];  const float* cloud_b= (const float*)d_in[7];
  const float* time_W = (const float*)d_in[8];  const float* time_b = (const float*)d_in[9];
  const float* other_W= (const float*)d_in[10]; const float* other_b= (const float*)d_in[11];
  const float* fi_W   = (const float*)d_in[12]; const float* fi_b   = (const float*)d_in[13];
  const float* enc_wih= (const float*)d_in[14]; const float* enc_whh= (const float*)d_in[15];
  const float* enc_bih= (const float*)d_in[16]; const float* enc_bhh= (const float*)d_in[17];
  const float* emb    = (const float*)d_in[18];
  const float* attn_W = (const float*)d_in[19]; const float* attn_b = (const float*)d_in[20];
  const float* dec_wih= (const float*)d_in[21]; const float* dec_whh= (const float*)d_in[22];
  const float* dec_bih= (const float*)d_in[23]; const float* dec_bhh= (const float*)d_in[24];
  const float* out_W  = (const float*)d_in[25]; const float* out_b  = (const float*)d_in[26];
  float* out = (float*)d_out;
  char* ws = (char*)d_ws;

  int*            arrE    = (int*)(ws + 0);                        // 64 x 32B
  int*            arrH    = (int*)(ws + 4096);                     // 128 x 64B
  int*            arrW    = (int*)(ws + 12288);                    // 64 x 32B
  int*            relE    = (int*)(ws + 14336);                    // 8 x 128B
  int*            relD    = (int*)(ws + 15360);                    // 8 x 128B
  float*          zbias   = (float*)(ws + 16384);                  // 12 KB zeros
  float*          Mf      = (float*)(ws + 32768);
  float*          b0v     = (float*)(ws + 98304);
  float*          hfp     = (float*)(ws + 102400);                 // 128 KB
  unsigned short* hcat    = (unsigned short*)(ws + 233472);        // 8 MB [2048][2048]
  unsigned short* keys_bf = (unsigned short*)(ws + 8622080);       // 8 MB
  unsigned short* enc_bf  = (unsigned short*)(ws + 17010688);      // 8 MB
  float*          w_all   = (float*)(ws + 25399296);               // 1 MB [63][32][128]
  float*          gi_e    = (float*)(ws + 26447872);               // 24 MB
  unsigned short* xeT     = (unsigned short*)(ws + 51613696);      // 24 MB [3072][4096]
  float*          gi_all  = (float*)(ws + 76779520);               // 48 MB
  unsigned short* proj_bf = (unsigned short*)(ws + 127111168);     // 8 MB
  unsigned short* e_bf    = (unsigned short*)(ws + 135499776);     // 4 MB
  unsigned short* wihE_bf = (unsigned short*)(ws + 139694080);     // 6 MB
  unsigned short* attnW_bf= (unsigned short*)(ws + 145985536);     // 2 MB
  unsigned short* wihD_bf = (unsigned short*)(ws + 148082688);     // 6 MB (emb cols)
  unsigned short* wihDc_bf= (unsigned short*)(ws + 154374144);     // 6 MB (ctx cols)
  unsigned short* outW_bf = (unsigned short*)(ws + 26447872);      // aliases dead gi_e/xeT/gi_all

  // zero flags + zbias + hcat padding rows (2016..2047)
  hipMemsetAsync(ws, 0, 32768, stream);
  hipMemsetAsync(ws + 233472 + (size_t)2016 * 2048 * 2, 0, 32 * 2048 * 2, stream);

  // weight conversions
  k_conv<<<1536, 256, 0, stream>>>(enc_wih, wihE_bf, 393216);
  k_conv<<<512, 256, 0, stream>>>(attn_W, attnW_bf, 131072);
  k_conv_str<<<3072, 256, 0, stream>>>(dec_wih, wihD_bf, 0);
  k_conv_str<<<3072, 256, 0, stream>>>(dec_wih, wihDc_bf, 1024);

  // feature pipeline
  k_fold<<<68, 256, 0, stream>>>(temp_W, temp_b, hum_W, hum_b, cloud_W, cloud_b,
                                 time_W, time_b, other_W, other_b, fi_W, fi_b, Mf, b0v);
  k_proj<<<dim3(4096, 4), 256, 0, stream>>>(features, Mf, b0v, proj_bf);

  // encoder input gates
  gemm_bf<0><<<768, 256, 0, stream>>>(proj_bf, wihE_bf, enc_bih, gi_all, nullptr,
                                      32, 1024, 1024, 1024, 3072, 0);
  // encoder scan (+ heaters)
  k_enc_scan<<<256, 256, 0, stream>>>(gi_all, enc_whh, enc_bhh, hfp, enc_bf, arrE, relE);

  // attention keys (bf16)
  gemm_bf<1><<<256, 256, 0, stream>>>(enc_bf, attnW_bf, attn_b, nullptr, keys_bf,
                                      32, 1024, 1024, 1024, 1024, 0);
  // decoder embedding-path gates
  k_gather_e<<<2048, 256, 0, stream>>>(toks, emb, e_bf);
  gemm_bf<0><<<384, 256, 0, stream>>>(e_bf, wihD_bf, dec_bih, gi_e, nullptr,
                                      16, 1024, 1024, 1024, 3072, 0);
  // ctx-path projection: xeT[j'][b*128+s] = (Wx*enc)
  gemm_bf<3><<<768, 256, 0, stream>>>(enc_bf, wihDc_bf, zbias, nullptr, xeT,
                                      32, 1024, 1024, 1024, 0, 0);
  // decoder scan (64 attn + 128 GRU + master + heaters)
  k_dec_scan<<<256, 256, 0, stream>>>(gi_e, dec_whh, dec_bhh, keys_bf, enc_bf,
                                      hcat, hfp, xeT, w_all, arrW, arrH, relD);
  // ctx assembly for the output concat (off critical path)
  k_ctx<<<dim3(32, 8), 256, 0, stream>>>(w_all, enc_bf, hcat);

  // batched output projection in two N-halves
  k_conv<<<2048, 256, 0, stream>>>(out_W, outW_bf, 4096000);
  gemm_bf<2><<<2000, 256, 0, stream>>>(hcat, outW_bf, out_b, out, nullptr,
                                       16, 2048, 2048, 2048, 0, 0);
  k_conv<<<2048, 256, 0, stream>>>(out_W + (size_t)16000 * 2048, outW_bf, 4096000);
  gemm_bf<2><<<2000, 256, 0, stream>>>(hcat, outW_bf, out_b + 16000, out, nullptr,
                                       16, 2048, 2048, 2048, 0, 16000);
  // out[:, 0, :] one-hot
  k_onehot<<<4000, 256, 0, stream>>>(toks, out);
}

// Round 14
// 2614.676 us; speedup vs baseline: 1.0592x; 1.0592x over previous
//
#include <hip/hip_runtime.h>

typedef float f32x4 __attribute__((ext_vector_type(4)));
typedef __bf16 bf16x8 __attribute__((ext_vector_type(8)));

#define DI static __device__ __forceinline__

DI unsigned short f2bf(float f) {
  unsigned u = __float_as_uint(f);
  u = (u + 0x7fffu + ((u >> 16) & 1u)) >> 16;
  return (unsigned short)u;
}
DI unsigned pk2(float lo, float hi) {
  return (unsigned)f2bf(lo) | ((unsigned)f2bf(hi) << 16);
}
DI float bflo(unsigned u) { return __uint_as_float(u << 16); }
DI float bfhi(unsigned u) { return __uint_as_float(u & 0xffff0000u); }
DI float sigm(float x) { return 1.0f / (1.0f + expf(-x)); }

DI void gl_lds16(const unsigned short* g, unsigned short* l) {
  __builtin_amdgcn_global_load_lds(
      (const __attribute__((address_space(1))) unsigned int*)g,
      (__attribute__((address_space(3))) unsigned int*)l, 16, 0, 0);
}

DI void st64_sc1(unsigned long long* p, unsigned long long v) {
  __hip_atomic_store(p, v, __ATOMIC_RELAXED, __HIP_MEMORY_SCOPE_AGENT);
}
DI int ldw(const int* p) {
  return __hip_atomic_load(p, __ATOMIC_RELAXED, __HIP_MEMORY_SCOPE_AGENT);
}
DI void stw(int* p, int v) {
  __hip_atomic_store(p, v, __ATOMIC_RELAXED, __HIP_MEMORY_SCOPE_AGENT);
}

DI void burn(int n) {
  float x = (float)(int)threadIdx.x;
#pragma unroll 1
  for (int i = 0; i < n; ++i) x = __builtin_fmaf(x, 1.0000001f, 1e-9f);
  asm volatile("" :: "v"(x));
}

// Wait on a replicated release word: ONE load per wave (lane 0), broadcast.
DI void waitrel(const int* relbase, int repl, int target) {
  const int* w = relbase + repl * 32;    // 128B-spaced replicas
  for (;;) {
    int v = 0;
    if ((threadIdx.x & 63) == 0) v = ldw(w);
    v = __shfl(v, 0);
    if (v >= target) break;
    burn(60);
  }
  asm volatile("" ::: "memory");
}
DI void strel(int* relbase, int v) {
  int l = threadIdx.x & 63;
  if (l < 8) stw(relbase + l * 32, v);
}

// ---------------------------------------------------------------------------
__global__ void k_fold(const float* __restrict__ tW, const float* __restrict__ tb,
                       const float* __restrict__ hW, const float* __restrict__ hb,
                       const float* __restrict__ cW, const float* __restrict__ cb,
                       const float* __restrict__ tiW, const float* __restrict__ tib,
                       const float* __restrict__ oW, const float* __restrict__ ob,
                       const float* __restrict__ fiW, const float* __restrict__ fib,
                       float* __restrict__ M, float* __restrict__ b0v)
{
  int g = blockIdx.x * 256 + threadIdx.x;
  if (g >= 1024 * 17) return;
  int h = g / 17, f = g - h * 17;
  const float* fw = fiW + (size_t)h * 2048;
  float s = 0.f;
  if (f == 16) {
    for (int k = 0; k < 256; ++k) s += fw[k] * tb[k];
    for (int k = 0; k < 256; ++k) s += fw[256 + k] * hb[k];
    for (int k = 0; k < 256; ++k) s += fw[512 + k] * cb[k];
    for (int k = 0; k < 256; ++k) s += fw[768 + k] * tib[k];
    for (int r = 0; r < 1024; ++r) s += fw[1024 + r] * ob[r];
    b0v[h] = s + fib[h];
  } else if (f == 0) {
    for (int k = 0; k < 256; ++k) s += fw[k] * tW[k];
    M[h * 16 + 0] = s;
  } else if (f == 1) {
    for (int k = 0; k < 256; ++k) s += fw[256 + k] * hW[k];
    M[h * 16 + 1] = s;
  } else if (f == 2) {
    for (int k = 0; k < 256; ++k) s += fw[512 + k] * cW[k];
    M[h * 16 + 2] = s;
  } else if (f == 11) {
    for (int k = 0; k < 256; ++k) s += fw[768 + k] * tiW[2 * k];
    M[h * 16 + 11] = s;
  } else if (f == 12) {
    for (int k = 0; k < 256; ++k) s += fw[768 + k] * tiW[2 * k + 1];
    M[h * 16 + 12] = s;
  } else {
    int col = (f <= 10) ? (f - 3) : (f - 5);
    for (int r = 0; r < 1024; ++r) s += fw[1024 + r] * oW[r * 11 + col];
    M[h * 16 + f] = s;
  }
}

__global__ __launch_bounds__(256)
void k_proj(const float* __restrict__ feat, const float* __restrict__ M,
            const float* __restrict__ b0v, unsigned short* __restrict__ proj)
{
  __shared__ float ft[16];
  int bs = blockIdx.x;
  int h = blockIdx.y * 256 + threadIdx.x;
  if (threadIdx.x < 16) ft[threadIdx.x] = feat[bs * 16 + threadIdx.x];
  __syncthreads();
  float sum = b0v[h];
  const float* mr = M + h * 16;
#pragma unroll
  for (int f = 0; f < 16; ++f) sum += mr[f] * ft[f];
  proj[(size_t)bs * 1024 + h] = f2bf(tanhf(sum));
}

__global__ void k_conv(const float* __restrict__ s, unsigned short* __restrict__ d, int n8)
{
  for (long i = (long)blockIdx.x * 256 + threadIdx.x; i < n8; i += (long)gridDim.x * 256) {
    const float* p = s + i * 8;
    f32x4 a = *(const f32x4*)p, b = *(const f32x4*)(p + 4);
    uint4 o;
    o.x = pk2(a[0], a[1]); o.y = pk2(a[2], a[3]);
    o.z = pk2(b[0], b[1]); o.w = pk2(b[2], b[3]);
    *(uint4*)(d + i * 8) = o;
  }
}

__global__ void k_conv_str(const float* __restrict__ s, unsigned short* __restrict__ d, int coff)
{
  int r = blockIdx.x;
  int c = threadIdx.x * 4;
  f32x4 a = *(const f32x4*)(s + (size_t)r * 2048 + coff + c);
  uint2 o; o.x = pk2(a[0], a[1]); o.y = pk2(a[2], a[3]);
  *(uint2*)(d + (size_t)r * 1024 + c) = o;
}

__global__ void k_gather_e(const int* __restrict__ toks, const float* __restrict__ emb,
                           unsigned short* __restrict__ e_bf)
{
  int row = blockIdx.x;               // 2048
  int t = row >> 5, b = row & 31;
  unsigned short* dst = e_bf + (size_t)row * 1024 + threadIdx.x * 4;
  if (t < 63) {
    int tok = toks[b * 64 + t];
    f32x4 a = *(const f32x4*)(emb + (size_t)tok * 1024 + threadIdx.x * 4);
    uint2 o; o.x = pk2(a[0], a[1]); o.y = pk2(a[2], a[3]);
    *(uint2*)dst = o;
  } else {
    uint2 o; o.x = 0u; o.y = 0u;
    *(uint2*)dst = o;
  }
}

__global__ void k_onehot(const int* __restrict__ toks, float* __restrict__ out)
{
  int i = blockIdx.x * 256 + threadIdx.x;
  if (i >= 32 * 32000) return;
  int b = i / 32000, v = i - b * 32000;
  out[(size_t)b * 64 * 32000 + v] = (v == toks[0]) ? 1.0f : 0.0f;
}

// ---------------------------------------------------------------------------
// bf16 MFMA GEMM: C[M,N] = A[M,K]*B[N,K]^T + bias[N]
// MODE 0: f32 C; MODE 1: bf16 C; MODE 2: decoder-output remap; MODE 3: bf16 C^T
// ---------------------------------------------------------------------------
template<int MODE>
__global__ __launch_bounds__(256)
void gemm_bf(const unsigned short* __restrict__ A, const unsigned short* __restrict__ B,
             const float* __restrict__ bias, float* __restrict__ Cf,
             unsigned short* __restrict__ Cb,
             int tiles_m, int K, int lda, int ldb, int ldc, int coloff)
{
  __shared__ unsigned short As[4096];
  __shared__ unsigned short Bs[4096];
  const int nblk = gridDim.x;
  const int cpx = nblk >> 3;
  const int bid = blockIdx.x;
  const int id = (bid & 7) * cpx + (bid >> 3);
  const int tm = id % tiles_m, tn = id / tiles_m;
  const int tid = threadIdx.x;
  const int lane = tid & 63, wave = tid >> 6;
  const int wm = (wave & 1) << 6, wn = (wave >> 1) << 6;
  const int r0 = tid >> 2, kc0 = (tid & 3) << 3;
  const unsigned short* ga0 = A + (size_t)(tm * 128 + r0) * lda + kc0;
  const unsigned short* ga1 = A + (size_t)(tm * 128 + 64 + r0) * lda + kc0;
  const unsigned short* gb0 = B + (size_t)(tn * 128 + r0) * ldb + kc0;
  const unsigned short* gb1 = B + (size_t)(tn * 128 + 64 + r0) * ldb + kc0;
  const int lr = lane & 15, lkb = (lane >> 4) << 3;

  f32x4 acc[4][4];
#pragma unroll
  for (int m = 0; m < 4; ++m)
#pragma unroll
    for (int n = 0; n < 4; ++n) { acc[m][n][0]=0.f; acc[m][n][1]=0.f; acc[m][n][2]=0.f; acc[m][n][3]=0.f; }

  for (int kt = 0; kt < K; kt += 32) {
    __syncthreads();
    gl_lds16(ga0 + kt, &As[tid * 8]);
    gl_lds16(ga1 + kt, &As[(tid + 256) * 8]);
    gl_lds16(gb0 + kt, &Bs[tid * 8]);
    gl_lds16(gb1 + kt, &Bs[(tid + 256) * 8]);
    __syncthreads();
    bf16x8 af[4], bfv[4];
#pragma unroll
    for (int m = 0; m < 4; ++m) af[m] = *(const bf16x8*)&As[(wm + m * 16 + lr) * 32 + lkb];
#pragma unroll
    for (int n = 0; n < 4; ++n) bfv[n] = *(const bf16x8*)&Bs[(wn + n * 16 + lr) * 32 + lkb];
#pragma unroll
    for (int m = 0; m < 4; ++m)
#pragma unroll
      for (int n = 0; n < 4; ++n)
        acc[m][n] = __builtin_amdgcn_mfma_f32_16x16x32_bf16(af[m], bfv[n], acc[m][n], 0, 0, 0);
  }

#pragma unroll
  for (int m = 0; m < 4; ++m) {
    int rb = tm * 128 + wm + m * 16 + ((lane >> 4) << 2);
#pragma unroll
    for (int n = 0; n < 4; ++n) {
      int c = tn * 128 + wn + n * 16 + lr;
      float bb = bias[c];
#pragma unroll
      for (int i = 0; i < 4; ++i) {
        float v = acc[m][n][i] + bb;
        int r = rb + i;
        if (MODE == 0) {
          Cf[(size_t)r * ldc + c] = v;
        } else if (MODE == 1) {
          Cb[(size_t)r * ldc + c] = f2bf(v);
        } else if (MODE == 3) {
          Cb[(size_t)c * 4096 + r] = f2bf(v);
        } else {
          if (r < 2016) {
            int t = r >> 5, b2 = r & 31;
            Cf[((size_t)b2 * 64 + t + 1) * 32000 + coloff + c] = v;
          }
        }
      }
    }
  }
}

// ---------------------------------------------------------------------------
// Persistent encoder scan. 64 worker blocks + 1 master.
// ---------------------------------------------------------------------------
__global__ __launch_bounds__(256, 1)
void k_enc_scan(const float* __restrict__ gi_all, const float* __restrict__ whh,
                const float* __restrict__ bhh, float* __restrict__ hfp,
                unsigned short* __restrict__ enc_bf,
                int* __restrict__ arrE, int* __restrict__ relE)
{
  const int tid = threadIdx.x;
  const int blk = blockIdx.x;
  if (blk == 64) {
    if (tid < 64) {
      for (int g = 1; g <= 127; ++g) {
        for (;;) {
          int v = ldw(&arrE[tid << 3]);
          if (__all(v >= g)) break;
          burn(60);
        }
        asm volatile("" ::: "memory");
        strel(relE, g);
      }
    }
    return;
  }

  __shared__ unsigned short W[48 * 1024];
  __shared__ float Cred[4 * 2 * 3 * 64 * 4];
  const int lane = tid & 63, wave = tid >> 6;
  const int j0 = blk * 16;
  const int repl = blk & 7;

  for (int i = tid; i < 48 * 128; i += 256) {
    int r = i >> 7, c = i & 127;
    int gr = ((r >> 4) << 10) + j0 + (r & 15);
    const float* src = whh + ((size_t)gr << 10) + (c << 3);
    f32x4 a = *(const f32x4*)src, b = *(const f32x4*)(src + 4);
    uint4 o;
    o.x = pk2(a[0], a[1]); o.y = pk2(a[2], a[3]);
    o.z = pk2(b[0], b[1]); o.w = pk2(b[2], b[3]);
    *(uint4*)&W[(r << 10) + ((c ^ (r & 7)) << 3)] = o;
  }
  __syncthreads();

  int cb[2], cj[2], clb[2], creg[2], cm[2];
  float bh0[2], bh1[2], bh2[2];
  float hp[2] = {0.f, 0.f};
#pragma unroll
  for (int cc = 0; cc < 2; ++cc) {
    int cell = tid + (cc << 8);
    cb[cc] = cell >> 4; cj[cc] = cell & 15;
    clb[cc] = ((cb[cc] & 15) >> 2) * 16;
    creg[cc] = cb[cc] & 3; cm[cc] = cb[cc] >> 4;
    bh0[cc] = bhh[j0 + cj[cc]];
    bh1[cc] = bhh[1024 + j0 + cj[cc]];
    bh2[cc] = bhh[2048 + j0 + cj[cc]];
  }

#pragma unroll 1
  for (int s = 0; s < 128; ++s) {
    float gp[2][3];
#pragma unroll
    for (int cc = 0; cc < 2; ++cc) {
      const float* gi = gi_all + ((size_t)cb[cc] * 128 + s) * 3072 + j0 + cj[cc];
      gp[cc][0] = gi[0]; gp[cc][1] = gi[1024]; gp[cc][2] = gi[2048];
    }

    f32x4 acc[2][3];
#pragma unroll
    for (int m = 0; m < 2; ++m)
#pragma unroll
      for (int n = 0; n < 3; ++n) { acc[m][n][0]=0.f; acc[m][n][1]=0.f; acc[m][n][2]=0.f; acc[m][n][3]=0.f; }

    if (s > 0) {
      waitrel(relE, repl, s);
      const unsigned short* hr = enc_bf + (size_t)(s - 1) * 1024;
      const int k0 = wave << 8;
      bf16x8 af[2][8];
#pragma unroll
      for (int kk = 0; kk < 8; ++kk) {
        int k = k0 + kk * 32 + ((lane >> 4) << 3);
        af[0][kk] = *(const bf16x8*)(hr + (size_t)(lane & 15) * 131072 + k);
        af[1][kk] = *(const bf16x8*)(hr + (size_t)(16 + (lane & 15)) * 131072 + k);
      }
#pragma unroll
      for (int kk = 0; kk < 8; ++kk) {
        int c = ((k0 + kk * 32) >> 3) + (lane >> 4);
#pragma unroll
        for (int n = 0; n < 3; ++n) {
          int wr = n * 16 + (lane & 15);
          bf16x8 bfr = *(const bf16x8*)&W[(wr << 10) + ((c ^ (wr & 7)) << 3)];
          acc[0][n] = __builtin_amdgcn_mfma_f32_16x16x32_bf16(af[0][kk], bfr, acc[0][n], 0, 0, 0);
          acc[1][n] = __builtin_amdgcn_mfma_f32_16x16x32_bf16(af[1][kk], bfr, acc[1][n], 0, 0, 0);
        }
      }
    }
#pragma unroll
    for (int m = 0; m < 2; ++m)
#pragma unroll
      for (int n = 0; n < 3; ++n)
        *(f32x4*)&Cred[((((wave * 2 + m) * 3 + n) * 64) + lane) << 2] = acc[m][n];
    __syncthreads();

    float h2v[2];
#pragma unroll
    for (int cc = 0; cc < 2; ++cc) {
      int lj = clb[cc] + cj[cc], reg = creg[cc], m = cm[cc];
      float Cr = 0.f, Cz = 0.f, Cn = 0.f;
#pragma unroll
      for (int w = 0; w < 4; ++w) {
        Cr += Cred[((((w * 2 + m) * 3 + 0) * 64 + lj) << 2) + reg];
        Cz += Cred[((((w * 2 + m) * 3 + 1) * 64 + lj) << 2) + reg];
        Cn += Cred[((((w * 2 + m) * 3 + 2) * 64 + lj) << 2) + reg];
      }
      float r = sigm(gp[cc][0] + Cr + bh0[cc]);
      float z = sigm(gp[cc][1] + Cz + bh1[cc]);
      float n = tanhf(gp[cc][2] + r * (Cn + bh2[cc]));
      float h2 = (1.f - z) * n + z * hp[cc];
      h2v[cc] = h2; hp[cc] = h2;
    }
    if (s == 127) {
      hfp[cb[0] * 1024 + j0 + cj[0]] = h2v[0];
      hfp[cb[1] * 1024 + j0 + cj[1]] = h2v[1];
    }
#pragma unroll
    for (int cc = 0; cc < 2; ++cc) {
      unsigned short sv = f2bf(h2v[cc]);
      unsigned p = (unsigned)sv | (((unsigned)__shfl_xor((int)(unsigned)sv, 1)) << 16);
      unsigned q = (unsigned)__shfl_xor((int)p, 2);
      if ((tid & 3) == 0) {
        unsigned long long dv = (unsigned long long)p | ((unsigned long long)q << 32);
        st64_sc1((unsigned long long*)&enc_bf[((size_t)cb[cc] * 128 + s) * 1024 + j0 + cj[cc]], dv);
      }
    }
    __syncthreads();
    if (tid == 0) stw(&arrE[blk << 3], s + 1);
  }
}

// ---------------------------------------------------------------------------
// Persistent decoder scan. 64 attn (keys-in-LDS, raw-e publish) + 128 GRU
// (xeT slice in REGISTERS, t-invariant) + 1 master (193 blocks).
// relD monotonic: 2t+1 = e(t) ready, 2t+2 = h(t) ready.
// ---------------------------------------------------------------------------
__global__ __launch_bounds__(256, 1)
void k_dec_scan(const float* __restrict__ gi_e, const float* __restrict__ whh,
                const float* __restrict__ bhh,
                const unsigned short* __restrict__ keys,
                const unsigned short* __restrict__ enc_bf,
                unsigned short* __restrict__ hcat, const float* __restrict__ hfp0,
                const unsigned short* __restrict__ xeT, float* __restrict__ w_all,
                int* __restrict__ arrW, int* __restrict__ arrH,
                int* __restrict__ relD)
{
  static __shared__ __attribute__((aligned(16))) char smem[135168];
  const int tid = threadIdx.x;
  const int blk = blockIdx.x;
  const int repl = blk & 7;

  if (blk == 192) {                        // master
    if (tid < 64) {
      for (int t = 0; t < 63; ++t) {
        for (;;) {                         // all 64 attn halves published e(t)
          int v = ldw(&arrW[tid << 3]);
          if (__all(v >= t + 1)) break;
          burn(60);
        }
        asm volatile("" ::: "memory");
        strel(relD, 2 * t + 1);
        for (;;) {                         // all 128 GRU blocks published h(t)
          int v0 = ldw(&arrH[(tid * 2) << 4]);
          int v1 = ldw(&arrH[(tid * 2 + 1) << 4]);
          if (__all(v0 >= t + 1 && v1 >= t + 1)) break;
          burn(60);
        }
        asm volatile("" ::: "memory");
        strel(relD, 2 * t + 2);
      }
    }
    return;
  }

  if (blk < 64) {
    // ------------------------- attention half-blocks ----------------------
    unsigned short* Ks = (unsigned short*)smem;            // 64 x 1024 bf16 (128KB)
    unsigned short* hsh = (unsigned short*)(smem + 131072); // 1024 bf16
    float* parr = (float*)(smem + 133120);                  // 4 x 64 f32
    const int b = blk >> 1, half = blk & 1;
    const int lane = tid & 63, wave = tid >> 6;

    // stage this half's 64 key rows into LDS, XOR-swizzled 16B chunks
    for (int i = tid; i < 64 * 128; i += 256) {
      int s = i >> 7, c = i & 127;
      uint4 kv = *(const uint4*)(keys + ((size_t)(b * 128 + half * 64 + s) << 10) + (c << 3));
      *(uint4*)&Ks[(s << 10) + ((c ^ (s & 7)) << 3)] = kv;
    }
    __syncthreads();

#pragma unroll 1
    for (int t = 0; t < 63; ++t) {
      if (t) waitrel(relD, repl, 2 * t);   // h(t-1) published
      const unsigned short* hsrc = (t == 0)
          ? (enc_bf + (size_t)b * 131072 + (size_t)127 * 1024)
          : (hcat + ((size_t)(t - 1) * 32 + b) * 2048);
      *(uint2*)&hsh[tid * 4] = *(const uint2*)(hsrc + tid * 4);
      __syncthreads();
      // wave handles k quarter; lane = s row
      float a0 = 0.f, a1 = 0.f;
#pragma unroll 8
      for (int i = 0; i < 32; i += 2) {
        int c0 = wave * 32 + i, c1 = c0 + 1;
        uint4 kv0 = *(const uint4*)&Ks[(lane << 10) + ((c0 ^ (lane & 7)) << 3)];
        uint4 kv1 = *(const uint4*)&Ks[(lane << 10) + ((c1 ^ (lane & 7)) << 3)];
        uint4 hv0 = *(const uint4*)&hsh[c0 << 3];
        uint4 hv1 = *(const uint4*)&hsh[c1 << 3];
        a0 += bflo(kv0.x) * bflo(hv0.x) + bfhi(kv0.x) * bfhi(hv0.x)
            + bflo(kv0.y) * bflo(hv0.y) + bfhi(kv0.y) * bfhi(hv0.y)
            + bflo(kv0.z) * bflo(hv0.z) + bfhi(kv0.z) * bfhi(hv0.z)
            + bflo(kv0.w) * bflo(hv0.w) + bfhi(kv0.w) * bfhi(hv0.w);
        a1 += bflo(kv1.x) * bflo(hv1.x) + bfhi(kv1.x) * bfhi(hv1.x)
            + bflo(kv1.y) * bflo(hv1.y) + bfhi(kv1.y) * bfhi(hv1.y)
            + bflo(kv1.z) * bflo(hv1.z) + bfhi(kv1.z) * bfhi(hv1.z)
            + bflo(kv1.w) * bflo(hv1.w) + bfhi(kv1.w) * bfhi(hv1.w);
      }
      parr[wave * 64 + lane] = a0 + a1;
      __syncthreads();
      if (tid < 64) {
        float sc = (parr[tid] + parr[64 + tid] + parr[128 + tid] + parr[192 + tid]) * 0.03125f;
        float e = expf(sc);                // raw-e softmax: consumers normalize
        float eo = __shfl_xor(e, 1);
        if ((tid & 1) == 0) {
          unsigned long long dv = (unsigned long long)__float_as_uint(e)
                                | ((unsigned long long)__float_as_uint(eo) << 32);
          st64_sc1((unsigned long long*)(w_all + ((size_t)t * 32 + b) * 128 + half * 64 + tid), dv);
        }
      }
      __syncthreads();                     // drain e stores
      if (tid == 0) stw(&arrW[blk << 3], t + 1);
    }
    return;
  }

  // --------------------------- GRU blocks ---------------------------------
  unsigned short* Wh = (unsigned short*)smem;              // 32 x 1024 bf16 (64KB)
  float* Cred = (float*)(smem + 65536);                    // 16KB
  const int lane = tid & 63, wave = tid >> 6;
  const int gblk = blk - 64;               // 0..127
  const int j0 = gblk * 8;

  for (int i = tid; i < 32 * 128; i += 256) {
    int r = i >> 7, c = i & 127;
    int off = (r << 10) + ((c ^ (r & 7)) << 3);
    uint4 oh;
    oh.x = oh.y = oh.z = oh.w = 0u;
    if (r < 24) {
      int gr = ((r >> 3) << 10) + j0 + (r & 7);
      const float* sh = whh + ((size_t)gr << 10) + (c << 3);
      f32x4 a = *(const f32x4*)sh, b = *(const f32x4*)(sh + 4);
      oh.x = pk2(a[0], a[1]); oh.y = pk2(a[2], a[3]);
      oh.z = pk2(b[0], b[1]); oh.w = pk2(b[2], b[3]);
    }
    *(uint4*)&Wh[off] = oh;
  }
  __syncthreads();

  const int gb = tid >> 3, gj = tid & 7;
  const int glb = ((gb & 15) >> 2) * 16;
  const int greg = gb & 3, gm = gb >> 4;
  const float bh0 = bhh[j0 + gj];
  const float bh1 = bhh[1024 + j0 + gj];
  const float bh2 = bhh[2048 + j0 + gj];
  float hpv = hfp0[gb * 1024 + j0 + gj];

  // t-invariant xeT slice -> registers (48 uint4 = 768B/thread)
  uint4 x0v[16], x1v[16], x2v[16];
  {
    const unsigned short* x0 = xeT + ((size_t)(j0 + gj) << 12) + gb * 128;
    const unsigned short* x1 = xeT + ((size_t)(1024 + j0 + gj) << 12) + gb * 128;
    const unsigned short* x2 = xeT + ((size_t)(2048 + j0 + gj) << 12) + gb * 128;
#pragma unroll
    for (int i = 0; i < 16; ++i) {
      x0v[i] = *(const uint4*)(x0 + i * 8);
      x1v[i] = *(const uint4*)(x1 + i * 8);
      x2v[i] = *(const uint4*)(x2 + i * 8);
    }
  }

#pragma unroll 1
  for (int t = 0; t < 63; ++t) {
    const float* gie = gi_e + ((size_t)t * 32 + gb) * 3072 + j0 + gj;
    float g0 = gie[0], g1 = gie[1024], g2 = gie[2048];

    if (t) waitrel(relD, repl, 2 * t);     // h(t-1) published
    const unsigned short* abase;
    size_t astr;
    if (t == 0) { abase = enc_bf + (size_t)127 * 1024; astr = 131072; }
    else { abase = hcat + (size_t)(t - 1) * 32 * 2048; astr = 2048; }
    const int k0 = wave << 8;
    f32x4 acc[2][2];
#pragma unroll
    for (int m = 0; m < 2; ++m)
#pragma unroll
      for (int n = 0; n < 2; ++n) { acc[m][n][0]=0.f; acc[m][n][1]=0.f; acc[m][n][2]=0.f; acc[m][n][3]=0.f; }
    {
      bf16x8 af[2][8];
#pragma unroll
      for (int kk = 0; kk < 8; ++kk) {
        int k = k0 + kk * 32 + ((lane >> 4) << 3);
        af[0][kk] = *(const bf16x8*)(abase + (size_t)(lane & 15) * astr + k);
        af[1][kk] = *(const bf16x8*)(abase + (size_t)(16 + (lane & 15)) * astr + k);
      }
#pragma unroll
      for (int kk = 0; kk < 8; ++kk) {
        int c = ((k0 + kk * 32) >> 3) + (lane >> 4);
#pragma unroll
        for (int n = 0; n < 2; ++n) {
          int wr = n * 16 + (lane & 15);
          bf16x8 bfr = *(const bf16x8*)&Wh[(wr << 10) + ((c ^ (wr & 7)) << 3)];
          acc[0][n] = __builtin_amdgcn_mfma_f32_16x16x32_bf16(af[0][kk], bfr, acc[0][n], 0, 0, 0);
          acc[1][n] = __builtin_amdgcn_mfma_f32_16x16x32_bf16(af[1][kk], bfr, acc[1][n], 0, 0, 0);
        }
      }
    }
#pragma unroll
    for (int m = 0; m < 2; ++m)
#pragma unroll
      for (int n = 0; n < 2; ++n)
        *(f32x4*)&Cred[((((wave * 2 + m) * 2 + n) * 64) + lane) << 2] = acc[m][n];
    __syncthreads();

    // wait for raw e's, then ctx-path = (sum_s e_s * xe) / sum_s e_s
    waitrel(relD, repl, 2 * t + 1);
    const float* wrow = w_all + ((size_t)t * 32 + gb) * 128;
    float se = 0.f, cx0 = 0.f, cx1 = 0.f, cx2 = 0.f;
#pragma unroll
    for (int i = 0; i < 16; ++i) {
      f32x4 wa = *(const f32x4*)(wrow + i * 8);
      f32x4 wb2 = *(const f32x4*)(wrow + i * 8 + 4);
      se += (wa[0] + wa[1]) + (wa[2] + wa[3]) + (wb2[0] + wb2[1]) + (wb2[2] + wb2[3]);
      uint4 a0 = x0v[i], a1 = x1v[i], a2 = x2v[i];
      cx0 += wa[0]*bflo(a0.x) + wa[1]*bfhi(a0.x) + wa[2]*bflo(a0.y) + wa[3]*bfhi(a0.y)
           + wb2[0]*bflo(a0.z) + wb2[1]*bfhi(a0.z) + wb2[2]*bflo(a0.w) + wb2[3]*bfhi(a0.w);
      cx1 += wa[0]*bflo(a1.x) + wa[1]*bfhi(a1.x) + wa[2]*bflo(a1.y) + wa[3]*bfhi(a1.y)
           + wb2[0]*bflo(a1.z) + wb2[1]*bfhi(a1.z) + wb2[2]*bflo(a1.w) + wb2[3]*bfhi(a1.w);
      cx2 += wa[0]*bflo(a2.x) + wa[1]*bfhi(a2.x) + wa[2]*bflo(a2.y) + wa[3]*bfhi(a2.y)
           + wb2[0]*bflo(a2.z) + wb2[1]*bfhi(a2.z) + wb2[2]*bflo(a2.w) + wb2[3]*bfhi(a2.w);
    }
    float inv = 1.f / se;
    cx0 *= inv; cx1 *= inv; cx2 *= inv;

    {
      float Chr = 0.f, Chz = 0.f, Chn = 0.f;
#pragma unroll
      for (int w = 0; w < 4; ++w) {
        Chr += Cred[((((w * 2 + gm) * 2 + 0) * 64 + glb + gj) << 2) + greg];
        Chz += Cred[((((w * 2 + gm) * 2 + 0) * 64 + glb + gj + 8) << 2) + greg];
        Chn += Cred[((((w * 2 + gm) * 2 + 1) * 64 + glb + gj) << 2) + greg];
      }
      float r = sigm(g0 + cx0 + Chr + bh0);
      float z = sigm(g1 + cx1 + Chz + bh1);
      float n2 = tanhf(g2 + cx2 + r * (Chn + bh2));
      float h2 = (1.f - z) * n2 + z * hpv;
      hpv = h2;
      unsigned short sv = f2bf(h2);
      unsigned p = (unsigned)sv | (((unsigned)__shfl_xor((int)(unsigned)sv, 1)) << 16);
      unsigned q = (unsigned)__shfl_xor((int)p, 2);
      if ((tid & 3) == 0) {
        unsigned long long dv = (unsigned long long)p | ((unsigned long long)q << 32);
        st64_sc1((unsigned long long*)&hcat[((size_t)t * 32 + gb) * 2048 + j0 + gj], dv);
      }
    }
    __syncthreads();
    if (tid == 0) stw(&arrH[gblk << 4], t + 1);
  }
}

// ---------------------------------------------------------------------------
// Post-scan ctx assembly: hcat[t*32+b][1024+j] = sum_s w*enc / sum_s w
// ---------------------------------------------------------------------------
__global__ __launch_bounds__(256)
void k_ctx(const float* __restrict__ w_all, const unsigned short* __restrict__ enc_bf,
           unsigned short* __restrict__ hcat)
{
  __shared__ float wsh[8][128];
  __shared__ float inv[8];
  const int b = blockIdx.x, tg = blockIdx.y;
  const int t0 = tg * 8;
  const int nt = (t0 + 8 <= 63) ? 8 : (63 - t0);
  const int tid = threadIdx.x;
  for (int idx = tid; idx < 8 * 128; idx += 256) {
    int tt = idx >> 7, s = idx & 127;
    wsh[tt][s] = (tt < nt) ? w_all[((size_t)(t0 + tt) * 32 + b) * 128 + s] : 0.f;
  }
  __syncthreads();
  if (tid < 8) {
    float s = 0.f;
    for (int i = 0; i < 128; ++i) s += wsh[tid][i];
    inv[tid] = (tid < nt) ? 1.f / s : 0.f;
  }
  __syncthreads();
  const int j0 = tid * 4;
  f32x4 cacc[8];
#pragma unroll
  for (int tt = 0; tt < 8; ++tt) { cacc[tt][0]=0.f; cacc[tt][1]=0.f; cacc[tt][2]=0.f; cacc[tt][3]=0.f; }
  const unsigned short* eb = enc_bf + ((size_t)b << 17) + j0;
  for (int s = 0; s < 128; ++s) {
    uint2 ev = *(const uint2*)(eb + ((size_t)s << 10));
    float v0 = bflo(ev.x), v1 = bfhi(ev.x), v2 = bflo(ev.y), v3 = bfhi(ev.y);
#pragma unroll
    for (int tt = 0; tt < 8; ++tt) {
      float w = wsh[tt][s];
      cacc[tt][0] += w * v0; cacc[tt][1] += w * v1;
      cacc[tt][2] += w * v2; cacc[tt][3] += w * v3;
    }
  }
#pragma unroll
  for (int tt = 0; tt < 8; ++tt) {
    if (tt < nt) {
      float iv = inv[tt];
      uint2 co;
      co.x = pk2(cacc[tt][0] * iv, cacc[tt][1] * iv);
      co.y = pk2(cacc[tt][2] * iv, cacc[tt][3] * iv);
      *(uint2*)(hcat + ((size_t)(t0 + tt) * 32 + b) * 2048 + 1024 + j0) = co;
    }
  }
}

// ---------------------------------------------------------------------------
extern "C" void kernel_launch(void* const* d_in, const int* in_sizes, int n_in,
                              void* d_out, int out_size, void* d_ws, size_t ws_size,
                              hipStream_t stream)
{
  const float* features = (const float*)d_in[0];
  const int*   toks     = (const int*)d_in[1];
  const float* temp_W = (const float*)d_in[2];  const float* temp_b = (const float*)d_in[3];
  const float* hum_W  = (const float*)d_in[4];  const float* hum_b  = (const float*)d_in[5];
  const float* cloud_W= (const float*)d_in[6];  const float* cloud_b= (const float*)d_in[7];
  const float* time_W = (const float*)d_in[8];  const float* time_b = (const float*)d_in[9];
  const float* other_W= (const float*)d_in[10]; const float* other_b= (const float*)d_in[11];
  const float* fi_W   = (const float*)d_in[12]; const float* fi_b   = (const float*)d_in[13];
  const float* enc_wih= (const float*)d_in[14]; const float* enc_whh= (const float*)d_in[15];
  const float* enc_bih= (const float*)d_in[16]; const float* enc_bhh= (const float*)d_in[17];
  const float* emb    = (const float*)d_in[18];
  const float* attn_W = (const float*)d_in[19]; const float* attn_b = (const float*)d_in[20];
  const float* dec_wih= (const float*)d_in[21]; const float* dec_whh= (const float*)d_in[22];
  const float* dec_bih= (const float*)d_in[23]; const float* dec_bhh= (const float*)d_in[24];
  const float* out_W  = (const float*)d_in[25]; const float* out_b  = (const float*)d_in[26];
  float* out = (float*)d_out;
  char* ws = (char*)d_ws;

  int*            arrE    = (int*)(ws + 0);                        // 64 x 32B
  int*            arrH    = (int*)(ws + 4096);                     // 128 x 64B
  int*            arrW    = (int*)(ws + 12288);                    // 64 x 32B
  int*            relE    = (int*)(ws + 14336);                    // 8 x 128B
  int*            relD    = (int*)(ws + 15360);                    // 8 x 128B
  float*          zbias   = (float*)(ws + 16384);                  // 12 KB zeros
  float*          Mf      = (float*)(ws + 32768);
  float*          b0v     = (float*)(ws + 98304);
  float*          hfp     = (float*)(ws + 102400);                 // 128 KB
  unsigned short* hcat    = (unsigned short*)(ws + 233472);        // 8 MB [2048][2048]
  unsigned short* keys_bf = (unsigned short*)(ws + 8622080);       // 8 MB
  unsigned short* enc_bf  = (unsigned short*)(ws + 17010688);      // 8 MB
  float*          w_all   = (float*)(ws + 25399296);               // 1 MB [63][32][128]
  float*          gi_e    = (float*)(ws + 26447872);               // 24 MB
  unsigned short* xeT     = (unsigned short*)(ws + 51613696);      // 24 MB [3072][4096]
  float*          gi_all  = (float*)(ws + 76779520);               // 48 MB
  unsigned short* proj_bf = (unsigned short*)(ws + 127111168);     // 8 MB
  unsigned short* e_bf    = (unsigned short*)(ws + 135499776);     // 4 MB
  unsigned short* wihE_bf = (unsigned short*)(ws + 139694080);     // 6 MB
  unsigned short* attnW_bf= (unsigned short*)(ws + 145985536);     // 2 MB
  unsigned short* wihD_bf = (unsigned short*)(ws + 148082688);     // 6 MB (emb cols)
  unsigned short* wihDc_bf= (unsigned short*)(ws + 154374144);     // 6 MB (ctx cols)
  unsigned short* outW_bf = (unsigned short*)(ws + 26447872);      // aliases dead gi_e/xeT/gi_all

  // zero flags + zbias + hcat padding rows (2016..2047)
  hipMemsetAsync(ws, 0, 32768, stream);
  hipMemsetAsync(ws + 233472 + (size_t)2016 * 2048 * 2, 0, 32 * 2048 * 2, stream);

  // weight conversions
  k_conv<<<1536, 256, 0, stream>>>(enc_wih, wihE_bf, 393216);
  k_conv<<<512, 256, 0, stream>>>(attn_W, attnW_bf, 131072);
  k_conv_str<<<3072, 256, 0, stream>>>(dec_wih, wihD_bf, 0);
  k_conv_str<<<3072, 256, 0, stream>>>(dec_wih, wihDc_bf, 1024);

  // feature pipeline
  k_fold<<<68, 256, 0, stream>>>(temp_W, temp_b, hum_W, hum_b, cloud_W, cloud_b,
                                 time_W, time_b, other_W, other_b, fi_W, fi_b, Mf, b0v);
  k_proj<<<dim3(4096, 4), 256, 0, stream>>>(features, Mf, b0v, proj_bf);

  // encoder input gates
  gemm_bf<0><<<768, 256, 0, stream>>>(proj_bf, wihE_bf, enc_bih, gi_all, nullptr,
                                      32, 1024, 1024, 1024, 3072, 0);
  // encoder scan
  k_enc_scan<<<65, 256, 0, stream>>>(gi_all, enc_whh, enc_bhh, hfp, enc_bf, arrE, relE);

  // attention keys (bf16)
  gemm_bf<1><<<256, 256, 0, stream>>>(enc_bf, attnW_bf, attn_b, nullptr, keys_bf,
                                      32, 1024, 1024, 1024, 1024, 0);
  // decoder embedding-path gates
  k_gather_e<<<2048, 256, 0, stream>>>(toks, emb, e_bf);
  gemm_bf<0><<<384, 256, 0, stream>>>(e_bf, wihD_bf, dec_bih, gi_e, nullptr,
                                      16, 1024, 1024, 1024, 3072, 0);
  // ctx-path projection: xeT[j'][b*128+s] = (Wx*enc)
  gemm_bf<3><<<768, 256, 0, stream>>>(enc_bf, wihDc_bf, zbias, nullptr, xeT,
                                      32, 1024, 1024, 1024, 0, 0);
  // decoder scan (64 attn + 128 GRU + master)
  k_dec_scan<<<193, 256, 0, stream>>>(gi_e, dec_whh, dec_bhh, keys_bf, enc_bf,
                                      hcat, hfp, xeT, w_all, arrW, arrH, relD);
  // ctx assembly for the output concat (off critical path)
  k_ctx<<<dim3(32, 8), 256, 0, stream>>>(w_all, enc_bf, hcat);

  // batched output projection in two N-halves
  k_conv<<<2048, 256, 0, stream>>>(out_W, outW_bf, 4096000);
  gemm_bf<2><<<2000, 256, 0, stream>>>(hcat, outW_bf, out_b, out, nullptr,
                                       16, 2048, 2048, 2048, 0, 0);
  k_conv<<<2048, 256, 0, stream>>>(out_W + (size_t)16000 * 2048, outW_bf, 4096000);
  gemm_bf<2><<<2000, 256, 0, stream>>>(hcat, outW_bf, out_b + 16000, out, nullptr,
                                       16, 2048, 2048, 2048, 0, 16000);
  // out[:, 0, :] one-hot
  k_onehot<<<4000, 256, 0, stream>>>(toks, out);
}